// Round 5
// baseline (9035.443 us; speedup 1.0000x reference)
//
#include <hip/hip_runtime.h>
#include <stdint.h>

// ---------- types ----------
typedef __bf16 bf16x8 __attribute__((ext_vector_type(8)));
typedef float f32x4 __attribute__((ext_vector_type(4)));
typedef short s16x8 __attribute__((ext_vector_type(8)));

__device__ __forceinline__ unsigned short f2bf(float f) {
  unsigned u = __builtin_bit_cast(unsigned, f);
  u += 0x7fff + ((u >> 16) & 1);   // RNE
  return (unsigned short)(u >> 16);
}
__device__ __forceinline__ float bf2f(unsigned short b) {
  unsigned u = ((unsigned)b) << 16;
  return __builtin_bit_cast(float, u);
}

__device__ __forceinline__ void gload_lds16(const void* g, void* l) {
  __builtin_amdgcn_global_load_lds(
      (const __attribute__((address_space(1))) unsigned int*)g,
      (__attribute__((address_space(3))) unsigned int*)l, 16, 0, 0);
}

__device__ __forceinline__ f32x4 mfma16x16x32(bf16x8 a, bf16x8 b, f32x4 c) {
  return __builtin_amdgcn_mfma_f32_16x16x32_bf16(a, b, c, 0, 0, 0);
}

// ---------- fp32 -> bf16 convert ----------
__global__ void k_f32_to_bf16(const float* __restrict__ in,
                              unsigned short* __restrict__ out, int n4) {
  int i = blockIdx.x * blockDim.x + threadIdx.x;
  if (i < n4) {
    float4 v = ((const float4*)in)[i];
    ushort4 o;
    o.x = f2bf(v.x); o.y = f2bf(v.y); o.z = f2bf(v.z); o.w = f2bf(v.w);
    ((ushort4*)out)[i] = o;
  }
}

// ---------- bf16 GEMM: C[M,N] = A[M,K] * B[N,K]^T  (both K-contiguous) ----------
// 128x128 tile, BK=32, 256 threads (4 waves 2x2), 16x16x32 MFMA. (m97 structure)
// MODE: 0 = bf16 out, 1 = f32 out + bias, 2 = f32 out plain
template <int MODE>
__global__ __launch_bounds__(256) void k_gemm_bt(
    const unsigned short* __restrict__ A, const unsigned short* __restrict__ Bm,
    unsigned short* __restrict__ Cb, float* __restrict__ Cf,
    const float* __restrict__ bias, int M, int N, int K) {
  __shared__ unsigned short As[128 * 32];
  __shared__ unsigned short Bs[128 * 32];
  const int tid = threadIdx.x;
  const int lane = tid & 63;
  const int l15 = lane & 15, g = lane >> 4;
  const int wid = tid >> 6, wr = wid >> 1, wc = wid & 1;
  const long m0 = (long)blockIdx.y * 128, n0 = (long)blockIdx.x * 128;

  f32x4 acc[4][4] = {};

  for (int k0 = 0; k0 < K; k0 += 32) {
#pragma unroll
    for (int p = 0; p < 2; ++p) {
      int e = p * 256 + tid;            // 16B unit index
      int row = e >> 2, col = (e & 3) * 8;
      gload_lds16(A + (m0 + row) * K + k0 + col, (char*)As + e * 16);
      gload_lds16(Bm + (n0 + row) * K + k0 + col, (char*)Bs + e * 16);
    }
    __syncthreads();
    bf16x8 af[4], bfr[4];
#pragma unroll
    for (int i = 0; i < 4; ++i) {
      af[i]  = __builtin_bit_cast(bf16x8, *(const s16x8*)&As[(wr * 64 + i * 16 + l15) * 32 + g * 8]);
      bfr[i] = __builtin_bit_cast(bf16x8, *(const s16x8*)&Bs[(wc * 64 + i * 16 + l15) * 32 + g * 8]);
    }
#pragma unroll
    for (int mi = 0; mi < 4; ++mi)
#pragma unroll
      for (int ni = 0; ni < 4; ++ni)
        acc[mi][ni] = mfma16x16x32(af[mi], bfr[ni], acc[mi][ni]);
    __syncthreads();
  }

#pragma unroll
  for (int mi = 0; mi < 4; ++mi)
#pragma unroll
    for (int ni = 0; ni < 4; ++ni) {
      long col = n0 + wc * 64 + ni * 16 + l15;
#pragma unroll
      for (int r = 0; r < 4; ++r) {
        long row = m0 + wr * 64 + mi * 16 + g * 4 + r;
        if (MODE == 1)
          Cf[row * N + col] = acc[mi][ni][r] + bias[col];
        else if (MODE == 2)
          Cf[row * N + col] = acc[mi][ni][r];
        else
          Cb[row * N + col] = f2bf(acc[mi][ni][r]);
      }
    }
}

// ---------- in-place RoPE (fp32 qkv) on q,k of [B,N,3,H,D] ----------
__global__ void k_rope_f32(float* __restrict__ qkv,
                           const float* __restrict__ sin_t,
                           const float* __restrict__ cos_t) {
  int t = blockIdx.x * 256 + threadIdx.x;   // B*N*H*32 threads
  int d = t & 31;
  int h = (t >> 5) & 15;
  int n = (t >> 9) & 2047;
  int b = t >> 20;
  if (n < 4) return;
  long base = ((long)(b * 2048 + n)) * 3072 + h * 64;
  int sc = (n - 4) * 64;
  float cl = cos_t[sc + d], sl = sin_t[sc + d];
  float ch = cos_t[sc + d + 32], sh = sin_t[sc + d + 32];
  float qlo = qkv[base + d], qhi = qkv[base + d + 32];
  qkv[base + d]      = qlo * cl - qhi * sl;
  qkv[base + d + 32] = qhi * ch + qlo * sh;
  float klo = qkv[base + 1024 + d], khi = qkv[base + 1024 + d + 32];
  qkv[base + 1024 + d]      = klo * cl - khi * sl;
  qkv[base + 1024 + d + 32] = khi * ch + klo * sh;
}

// ---------- in-place RoPE (bf16 qkv) — fallback path ----------
__global__ void k_rope(unsigned short* __restrict__ qkv,
                       const float* __restrict__ sin_t,
                       const float* __restrict__ cos_t) {
  int t = blockIdx.x * 256 + threadIdx.x;
  int d = t & 31;
  int h = (t >> 5) & 15;
  int n = (t >> 9) & 2047;
  int b = t >> 20;
  if (n < 4) return;
  long base = ((long)(b * 2048 + n)) * 3072 + h * 64;
  int sc = (n - 4) * 64;
  float cl = cos_t[sc + d], sl = sin_t[sc + d];
  float ch = cos_t[sc + d + 32], sh = sin_t[sc + d + 32];
  float qlo = bf2f(qkv[base + d]), qhi = bf2f(qkv[base + d + 32]);
  qkv[base + d]      = f2bf(qlo * cl - qhi * sl);
  qkv[base + d + 32] = f2bf(qhi * ch + qlo * sh);
  float klo = bf2f(qkv[base + 1024 + d]), khi = bf2f(qkv[base + 1024 + d + 32]);
  qkv[base + 1024 + d]      = f2bf(klo * cl - khi * sl);
  qkv[base + 1024 + d + 32] = f2bf(khi * ch + klo * sh);
}

// ---------- simple attention, fp32 qkv ----------
// grid (512, 64); block 256 = 4 waves; one wave per query row.
__global__ __launch_bounds__(256) void k_attn_f32(
    const float* __restrict__ qkv, unsigned short* __restrict__ o) {
  __shared__ float Srow[4][2048];
  __shared__ float qs[4][64];
  const int tid = threadIdx.x;
  const int lane = tid & 63, wid = tid >> 6;
  const int bh = blockIdx.y, b = bh >> 4, h = bh & 15;
  const int q = blockIdx.x * 4 + wid;

  const long rowQ = ((long)(b * 2048 + q)) * 3072 + h * 64;
  qs[wid][lane] = qkv[rowQ + lane];
  __syncthreads();

  float sv[32];
  float lmax = -1e30f;
  const long kbase = ((long)b * 2048) * 3072 + 1024 + h * 64;
#pragma unroll 4
  for (int j = 0; j < 32; ++j) {
    int key = j * 64 + lane;
    const float4* kr = (const float4*)&qkv[kbase + (long)key * 3072];
    float s = 0.f;
#pragma unroll
    for (int c = 0; c < 16; ++c) {
      float4 u = kr[c];
      s += qs[wid][c * 4 + 0] * u.x + qs[wid][c * 4 + 1] * u.y +
           qs[wid][c * 4 + 2] * u.z + qs[wid][c * 4 + 3] * u.w;
    }
    sv[j] = s * 0.125f;
    lmax = fmaxf(lmax, sv[j]);
  }
#pragma unroll
  for (int d = 1; d < 64; d <<= 1) lmax = fmaxf(lmax, __shfl_xor(lmax, d));

  float lsum = 0.f;
#pragma unroll 4
  for (int j = 0; j < 32; ++j) {
    float p = __expf(sv[j] - lmax);
    lsum += p;
    Srow[wid][j * 64 + lane] = p;
  }
#pragma unroll
  for (int d = 1; d < 64; d <<= 1) lsum += __shfl_xor(lsum, d);
  __syncthreads();

  const long vbase = ((long)b * 2048) * 3072 + 2048 + h * 64 + lane;
  float a0 = 0.f, a1 = 0.f, a2 = 0.f, a3 = 0.f;
  for (int k = 0; k < 2048; k += 4) {
    a0 += Srow[wid][k + 0] * qkv[vbase + (long)(k + 0) * 3072];
    a1 += Srow[wid][k + 1] * qkv[vbase + (long)(k + 1) * 3072];
    a2 += Srow[wid][k + 2] * qkv[vbase + (long)(k + 2) * 3072];
    a3 += Srow[wid][k + 3] * qkv[vbase + (long)(k + 3) * 3072];
  }
  float acc = (a0 + a1) + (a2 + a3);
  o[((long)(b * 2048 + q)) * 1024 + h * 64 + lane] = f2bf(acc / lsum);
}

// ---------- simple attention, bf16 qkv — fallback path ----------
__global__ __launch_bounds__(256) void k_attn_simple(
    const unsigned short* __restrict__ qkv, unsigned short* __restrict__ o) {
  __shared__ float Srow[4][2048];
  __shared__ float qs[4][64];
  const int tid = threadIdx.x;
  const int lane = tid & 63, wid = tid >> 6;
  const int bh = blockIdx.y, b = bh >> 4, h = bh & 15;
  const int q = blockIdx.x * 4 + wid;

  const long rowQ = ((long)(b * 2048 + q)) * 3072 + h * 64;
  qs[wid][lane] = bf2f(qkv[rowQ + lane]);
  __syncthreads();

  float sv[32];
  float lmax = -1e30f;
  const long kbase = ((long)b * 2048) * 3072 + 1024 + h * 64;
#pragma unroll 4
  for (int j = 0; j < 32; ++j) {
    int key = j * 64 + lane;
    const ushort4* kr = (const ushort4*)&qkv[kbase + (long)key * 3072];
    float s = 0.f;
#pragma unroll
    for (int c = 0; c < 16; ++c) {
      ushort4 u = kr[c];
      s += qs[wid][c * 4 + 0] * bf2f(u.x) + qs[wid][c * 4 + 1] * bf2f(u.y) +
           qs[wid][c * 4 + 2] * bf2f(u.z) + qs[wid][c * 4 + 3] * bf2f(u.w);
    }
    sv[j] = s * 0.125f;
    lmax = fmaxf(lmax, sv[j]);
  }
#pragma unroll
  for (int d = 1; d < 64; d <<= 1) lmax = fmaxf(lmax, __shfl_xor(lmax, d));

  float lsum = 0.f;
#pragma unroll 4
  for (int j = 0; j < 32; ++j) {
    float p = __expf(sv[j] - lmax);
    lsum += p;
    Srow[wid][j * 64 + lane] = p;
  }
#pragma unroll
  for (int d = 1; d < 64; d <<= 1) lsum += __shfl_xor(lsum, d);
  __syncthreads();

  const long vbase = ((long)b * 2048) * 3072 + 2048 + h * 64 + lane;
  float a0 = 0.f, a1 = 0.f, a2 = 0.f, a3 = 0.f;
  for (int k = 0; k < 2048; k += 4) {
    a0 += Srow[wid][k + 0] * bf2f(qkv[vbase + (long)(k + 0) * 3072]);
    a1 += Srow[wid][k + 1] * bf2f(qkv[vbase + (long)(k + 1) * 3072]);
    a2 += Srow[wid][k + 2] * bf2f(qkv[vbase + (long)(k + 2) * 3072]);
    a3 += Srow[wid][k + 3] * bf2f(qkv[vbase + (long)(k + 3) * 3072]);
  }
  float acc = (a0 + a1) + (a2 + a3);
  o[((long)(b * 2048 + q)) * 1024 + h * 64 + lane] = f2bf(acc / lsum);
}

// ---------- launcher ----------
extern "C" void kernel_launch(void* const* d_in, const int* in_sizes, int n_in,
                              void* d_out, int out_size, void* d_ws, size_t ws_size,
                              hipStream_t stream) {
  const float* x      = (const float*)d_in[0];
  const float* sin_t  = (const float*)d_in[1];
  const float* cos_t  = (const float*)d_in[2];
  const float* w_qkv  = (const float*)d_in[3];
  const float* w_proj = (const float*)d_in[4];
  const float* b_proj = (const float*)d_in[5];
  float* out = (float*)d_out;

  char* ws = (char*)d_ws;
  unsigned short* xb     = (unsigned short*)(ws);                 // 16 MiB
  unsigned short* wqkvb  = (unsigned short*)(ws + (16l << 20));   // 6 MiB
  unsigned short* wprojb = (unsigned short*)(ws + (22l << 20));   // 2 MiB
  unsigned short* ob     = xb;  // alias: xb dead after QKV GEMM

  k_f32_to_bf16<<<8192, 256, 0, stream>>>(x, xb, 8388608 / 4);
  k_f32_to_bf16<<<3072, 256, 0, stream>>>(w_qkv, wqkvb, 3145728 / 4);
  k_f32_to_bf16<<<1024, 256, 0, stream>>>(w_proj, wprojb, 1048576 / 4);

  if (ws_size >= (size_t)(120l << 20)) {
    // fp32-qkv path: removes q/k/v bf16-rounding error in attention
    float* qkvf = (float*)(ws + (24l << 20));                     // 96 MiB
    k_gemm_bt<2><<<dim3(24, 64), 256, 0, stream>>>(xb, wqkvb, nullptr, qkvf,
                                                   nullptr, 8192, 3072, 1024);
    k_rope_f32<<<16384, 256, 0, stream>>>(qkvf, sin_t, cos_t);
    k_attn_f32<<<dim3(512, 64), 256, 0, stream>>>(qkvf, ob);
  } else {
    // proven-safe 72 MiB fallback (round-4 path)
    unsigned short* qkvb = (unsigned short*)(ws + (24l << 20));   // 48 MiB
    k_gemm_bt<0><<<dim3(24, 64), 256, 0, stream>>>(xb, wqkvb, qkvb, nullptr,
                                                   nullptr, 8192, 3072, 1024);
    k_rope<<<16384, 256, 0, stream>>>(qkvb, sin_t, cos_t);
    k_attn_simple<<<dim3(512, 64), 256, 0, stream>>>(qkvb, ob);
  }

  k_gemm_bt<1><<<dim3(8, 64), 256, 0, stream>>>(ob, wprojb, nullptr, out, b_proj,
                                                8192, 1024, 1024);
}

// Round 6
// 332.928 us; speedup vs baseline: 27.1393x; 27.1393x over previous
//
#include <hip/hip_runtime.h>
#include <stdint.h>

// ---------- types ----------
typedef __bf16 bf16x8 __attribute__((ext_vector_type(8)));
typedef float f32x4 __attribute__((ext_vector_type(4)));
typedef short s16x8 __attribute__((ext_vector_type(8)));
typedef unsigned int u32x2 __attribute__((ext_vector_type(2)));

__device__ __forceinline__ unsigned short f2bf(float f) {
  unsigned u = __builtin_bit_cast(unsigned, f);
  u += 0x7fff + ((u >> 16) & 1);   // RNE
  return (unsigned short)(u >> 16);
}
__device__ __forceinline__ float bf2f(unsigned short b) {
  unsigned u = ((unsigned)b) << 16;
  return __builtin_bit_cast(float, u);
}

__device__ __forceinline__ void gload_lds16(const void* g, void* l) {
  __builtin_amdgcn_global_load_lds(
      (const __attribute__((address_space(1))) unsigned int*)g,
      (__attribute__((address_space(3))) unsigned int*)l, 16, 0, 0);
}

__device__ __forceinline__ f32x4 mfma16x16x32(bf16x8 a, bf16x8 b, f32x4 c) {
  return __builtin_amdgcn_mfma_f32_16x16x32_bf16(a, b, c, 0, 0, 0);
}
__device__ __forceinline__ bf16x8 bc8(s16x8 v) { return __builtin_bit_cast(bf16x8, v); }

// ---------- fp32 -> bf16 convert ----------
__global__ void k_f32_to_bf16(const float* __restrict__ in,
                              unsigned short* __restrict__ out, int n4) {
  int i = blockIdx.x * blockDim.x + threadIdx.x;
  if (i < n4) {
    float4 v = ((const float4*)in)[i];
    ushort4 o;
    o.x = f2bf(v.x); o.y = f2bf(v.y); o.z = f2bf(v.z); o.w = f2bf(v.w);
    ((ushort4*)out)[i] = o;
  }
}

// ---------- QKV GEMM with fused RoPE + hi/lo-split epilogue ----------
// C[m, f] = sum_c x[m,c] * w_qkv[f,c];  m=(b,n), f = s*1024 + h*64 + d.
// Epilogue: s<2 -> RoPE (n>=4), split into hi+lo bf16 slabs [B*H, N, D];
//           s==2 -> V bf16 slab.
__global__ __launch_bounds__(256) void k_gemm_qkv(
    const unsigned short* __restrict__ A, const unsigned short* __restrict__ Bm,
    unsigned short* __restrict__ Qh, unsigned short* __restrict__ Ql,
    unsigned short* __restrict__ Kh, unsigned short* __restrict__ Kl,
    unsigned short* __restrict__ Vb,
    const float* __restrict__ sin_t, const float* __restrict__ cos_t) {
  const int M_K = 1024;            // GEMM K dim
  __shared__ unsigned short As[128 * 32];
  __shared__ unsigned short Bs[128 * 32];
  const int tid = threadIdx.x;
  const int lane = tid & 63;
  const int l15 = lane & 15, g = lane >> 4;
  const int wid = tid >> 6, wr = wid >> 1, wc = wid & 1;
  const long m0 = (long)blockIdx.y * 128, n0 = (long)blockIdx.x * 128;

  f32x4 acc[4][4] = {};

  for (int k0 = 0; k0 < M_K; k0 += 32) {
#pragma unroll
    for (int p = 0; p < 2; ++p) {
      int e = p * 256 + tid;
      int row = e >> 2, col = (e & 3) * 8;
      gload_lds16(A + (m0 + row) * M_K + k0 + col, (char*)As + e * 16);
      gload_lds16(Bm + (n0 + row) * M_K + k0 + col, (char*)Bs + e * 16);
    }
    __syncthreads();
    bf16x8 af[4], bfr[4];
#pragma unroll
    for (int i = 0; i < 4; ++i) {
      af[i]  = bc8(*(const s16x8*)&As[(wr * 64 + i * 16 + l15) * 32 + g * 8]);
      bfr[i] = bc8(*(const s16x8*)&Bs[(wc * 64 + i * 16 + l15) * 32 + g * 8]);
    }
#pragma unroll
    for (int mi = 0; mi < 4; ++mi)
#pragma unroll
      for (int ni = 0; ni < 4; ++ni)
        acc[mi][ni] = mfma16x16x32(af[mi], bfr[ni], acc[mi][ni]);
    __syncthreads();
  }

  // epilogue: col = n0 + wc*64 + ni*16 + l15 ; d = ni*16 + l15
  const int colbase = (int)n0 + wc * 64;
  const int s  = colbase >> 10;           // 0=q 1=k 2=v (uniform per wave-half)
  const int h  = (colbase >> 6) & 15;
#pragma unroll
  for (int mi = 0; mi < 4; ++mi)
#pragma unroll
    for (int r = 0; r < 4; ++r) {
      long m = m0 + wr * 64 + mi * 16 + g * 4 + r;
      int b = (int)(m >> 11), n = (int)(m & 2047);
      long slab = ((long)(b * 16 + h)) * 131072 + (long)n * 64;
      float v0 = acc[mi][0][r], v1 = acc[mi][1][r];
      float v2 = acc[mi][2][r], v3 = acc[mi][3][r];
      if (s == 2) {
        Vb[slab + l15]      = f2bf(v0);
        Vb[slab + 16 + l15] = f2bf(v1);
        Vb[slab + 32 + l15] = f2bf(v2);
        Vb[slab + 48 + l15] = f2bf(v3);
      } else {
        float o0 = v0, o1 = v1, o2 = v2, o3 = v3;
        if (n >= 4) {
          const float* cs = cos_t + (long)(n - 4) * 64;
          const float* sn = sin_t + (long)(n - 4) * 64;
          float c0 = cs[l15], c1 = cs[16 + l15], c2 = cs[32 + l15], c3 = cs[48 + l15];
          float s0 = sn[l15], s1 = sn[16 + l15], s2 = sn[32 + l15], s3 = sn[48 + l15];
          o0 = v0 * c0 - v2 * s0;  o1 = v1 * c1 - v3 * s1;
          o2 = v2 * c2 + v0 * s2;  o3 = v3 * c3 + v1 * s3;
        }
        unsigned short* H = (s == 0) ? Qh : Kh;
        unsigned short* L = (s == 0) ? Ql : Kl;
        unsigned short h0 = f2bf(o0); H[slab + l15]      = h0; L[slab + l15]      = f2bf(o0 - bf2f(h0));
        unsigned short h1 = f2bf(o1); H[slab + 16 + l15] = h1; L[slab + 16 + l15] = f2bf(o1 - bf2f(h1));
        unsigned short h2 = f2bf(o2); H[slab + 32 + l15] = h2; L[slab + 32 + l15] = f2bf(o2 - bf2f(h2));
        unsigned short h3 = f2bf(o3); H[slab + 48 + l15] = h3; L[slab + 48 + l15] = f2bf(o3 - bf2f(h3));
      }
    }
}

// ---------- generic bf16 GEMM (final projection), f32 out + bias ----------
__global__ __launch_bounds__(256) void k_gemm_proj(
    const unsigned short* __restrict__ A, const unsigned short* __restrict__ Bm,
    float* __restrict__ Cf, const float* __restrict__ bias, int M, int N, int K) {
  __shared__ unsigned short As[128 * 32];
  __shared__ unsigned short Bs[128 * 32];
  const int tid = threadIdx.x;
  const int lane = tid & 63;
  const int l15 = lane & 15, g = lane >> 4;
  const int wid = tid >> 6, wr = wid >> 1, wc = wid & 1;
  const long m0 = (long)blockIdx.y * 128, n0 = (long)blockIdx.x * 128;

  f32x4 acc[4][4] = {};

  for (int k0 = 0; k0 < K; k0 += 32) {
#pragma unroll
    for (int p = 0; p < 2; ++p) {
      int e = p * 256 + tid;
      int row = e >> 2, col = (e & 3) * 8;
      gload_lds16(A + (m0 + row) * K + k0 + col, (char*)As + e * 16);
      gload_lds16(Bm + (n0 + row) * K + k0 + col, (char*)Bs + e * 16);
    }
    __syncthreads();
    bf16x8 af[4], bfr[4];
#pragma unroll
    for (int i = 0; i < 4; ++i) {
      af[i]  = bc8(*(const s16x8*)&As[(wr * 64 + i * 16 + l15) * 32 + g * 8]);
      bfr[i] = bc8(*(const s16x8*)&Bs[(wc * 64 + i * 16 + l15) * 32 + g * 8]);
    }
#pragma unroll
    for (int mi = 0; mi < 4; ++mi)
#pragma unroll
      for (int ni = 0; ni < 4; ++ni)
        acc[mi][ni] = mfma16x16x32(af[mi], bfr[ni], acc[mi][ni]);
    __syncthreads();
  }

#pragma unroll
  for (int mi = 0; mi < 4; ++mi)
#pragma unroll
    for (int ni = 0; ni < 4; ++ni) {
      long col = n0 + wc * 64 + ni * 16 + l15;
#pragma unroll
      for (int r = 0; r < 4; ++r) {
        long row = m0 + wr * 64 + mi * 16 + g * 4 + r;
        Cf[row * N + col] = acc[mi][ni][r] + bias[col];
      }
    }
}

// ---------- MFMA flash attention ----------
// grid (32, 64); 256 thr = 4 waves x 16 queries.  All operands from packed
// [B*H, N, D] slabs.  Swapped QK^T with split-bf16 Q,K (fp32-accurate scores):
//   st[kt][r] = S^T[key = kt*16+g*4+r][q = l15]
// PV: P transposed via per-wave LDS (key==col identity), V transposed via
// reg-staged LDS writes; both consumed as contiguous swizzled ds_read_b128.
__global__ __launch_bounds__(256) void k_flash(
    const unsigned short* __restrict__ Qh, const unsigned short* __restrict__ Ql,
    const unsigned short* __restrict__ Kh, const unsigned short* __restrict__ Kl,
    const unsigned short* __restrict__ Vb, unsigned short* __restrict__ o) {
  __shared__ unsigned short KhS[64 * 64];
  __shared__ unsigned short KlS[64 * 64];
  __shared__ unsigned short VtS[64 * 64];      // Vt[d][key], dual-xor swizzled
  __shared__ unsigned short PS[4][16 * 64];    // per wave: P^T[q][key], swizzled
  const int tid = threadIdx.x;
  const int lane = tid & 63, wid = tid >> 6;
  const int l15 = lane & 15, g = lane >> 4;
  const int bh = blockIdx.y, b = bh >> 4, h = bh & 15;
  const int q0 = blockIdx.x * 64 + wid * 16;
  const long slab = (long)bh * 131072;         // 2048*64

  const long qrow = slab + (long)(q0 + l15) * 64;
  bf16x8 qh0 = bc8(*(const s16x8*)&Qh[qrow + g * 8]);
  bf16x8 qh1 = bc8(*(const s16x8*)&Qh[qrow + 32 + g * 8]);
  bf16x8 ql0 = bc8(*(const s16x8*)&Ql[qrow + g * 8]);
  bf16x8 ql1 = bc8(*(const s16x8*)&Ql[qrow + 32 + g * 8]);

  f32x4 ovt[4] = {};
  float mrun = -1e30f, lrun = 0.f;

  for (int t = 0; t < 32; ++t) {
    const int kv0 = t * 64;
    __syncthreads();                           // prev tile's PV done
    s16x8 vregA, vregB;
    {
      int u = tid;                             // p = 0
      int row = u >> 3, cu = u & 7, c = cu ^ (row & 7);
      gload_lds16(Kh + slab + (long)(kv0 + row) * 64 + c * 8, (char*)KhS + u * 16);
      gload_lds16(Kl + slab + (long)(kv0 + row) * 64 + c * 8, (char*)KlS + u * 16);
      vregA = *(const s16x8*)&Vb[slab + (long)(kv0 + row) * 64 + cu * 8];
    }
    {
      int u = 256 + tid;                       // p = 1
      int row = u >> 3, cu = u & 7, c = cu ^ (row & 7);
      gload_lds16(Kh + slab + (long)(kv0 + row) * 64 + c * 8, (char*)KhS + u * 16);
      gload_lds16(Kl + slab + (long)(kv0 + row) * 64 + c * 8, (char*)KlS + u * 16);
      vregB = *(const s16x8*)&Vb[slab + (long)(kv0 + row) * 64 + cu * 8];
    }
    __syncthreads();                           // K tiles + vregs ready

    // write Vt: layout swz = unit ^ (d&7) ^ (d>>3)
    {
      int u = tid, key = u >> 3, dchunk = u & 7;
#pragma unroll
      for (int i = 0; i < 8; ++i) {
        int d = dchunk * 8 + i;
        int swz = ((key >> 3) ^ i ^ dchunk) & 7;
        VtS[d * 64 + swz * 8 + (key & 7)] = (unsigned short)vregA[i];
      }
    }
    {
      int u = 256 + tid, key = u >> 3, dchunk = u & 7;
#pragma unroll
      for (int i = 0; i < 8; ++i) {
        int d = dchunk * 8 + i;
        int swz = ((key >> 3) ^ i ^ dchunk) & 7;
        VtS[d * 64 + swz * 8 + (key & 7)] = (unsigned short)vregB[i];
      }
    }

    // QK^T split: S = kh*qh + kh*ql + kl*qh
    f32x4 st[4];
#pragma unroll
    for (int kt = 0; kt < 4; ++kt) {
      f32x4 sacc = {};
#pragma unroll
      for (int kk = 0; kk < 2; ++kk) {
        int row = kt * 16 + l15;
        int uu = row * 8 + ((kk * 4 + g) ^ (row & 7));
        bf16x8 khf = bc8(*(const s16x8*)&KhS[uu * 8]);
        bf16x8 klf = bc8(*(const s16x8*)&KlS[uu * 8]);
        bf16x8 qhf = kk ? qh1 : qh0;
        bf16x8 qlf = kk ? ql1 : ql0;
        sacc = mfma16x16x32(khf, qhf, sacc);
        sacc = mfma16x16x32(khf, qlf, sacc);
        sacc = mfma16x16x32(klf, qhf, sacc);
      }
      st[kt] = sacc;
    }

    // online softmax (4 g-lanes per query)
    float tmax = -1e30f;
#pragma unroll
    for (int kt = 0; kt < 4; ++kt)
#pragma unroll
      for (int r = 0; r < 4; ++r) {
        st[kt][r] *= 0.125f;
        tmax = fmaxf(tmax, st[kt][r]);
      }
    tmax = fmaxf(tmax, __shfl_xor(tmax, 16));
    tmax = fmaxf(tmax, __shfl_xor(tmax, 32));
    float mnew = fmaxf(mrun, tmax);
    float corr = __expf(mrun - mnew);
    mrun = mnew;
    lrun *= corr;
#pragma unroll
    for (int dt = 0; dt < 4; ++dt) ovt[dt] *= corr;

    unsigned pb[4][2];
#pragma unroll
    for (int kt = 0; kt < 4; ++kt) {
      float p0 = __expf(st[kt][0] - mnew);
      float p1 = __expf(st[kt][1] - mnew);
      float p2 = __expf(st[kt][2] - mnew);
      float p3 = __expf(st[kt][3] - mnew);
      lrun += p0 + p1 + p2 + p3;
      pb[kt][0] = (unsigned)f2bf(p0) | ((unsigned)f2bf(p1) << 16);
      pb[kt][1] = (unsigned)f2bf(p2) | ((unsigned)f2bf(p3) << 16);
    }
    // write P^T to per-wave LDS (16B-unit swizzle: unit ^ (q&7))
#pragma unroll
    for (int kt = 0; kt < 4; ++kt) {
      int up = ((kt * 2 + (g >> 1)) ^ (l15 & 7)) & 7;
      u32x2 w = {pb[kt][0], pb[kt][1]};
      *(u32x2*)&PS[wid][l15 * 64 + up * 8 + (g & 1) * 4] = w;
    }
    __syncthreads();                           // Vt + P visible

    // PV: O^T[d][q] += Vt-frag x P-frag
#pragma unroll
    for (int khalf = 0; khalf < 2; ++khalf) {
      int ub = ((khalf * 4 + g) ^ (l15 & 7)) & 7;
      bf16x8 pf = bc8(*(const s16x8*)&PS[wid][l15 * 64 + ub * 8]);
#pragma unroll
      for (int dt = 0; dt < 4; ++dt) {
        int d = dt * 16 + l15;
        int swzr = ((khalf * 4 + g) ^ (d & 7) ^ ((d >> 3) & 7)) & 7;
        bf16x8 vf = bc8(*(const s16x8*)&VtS[d * 64 + swzr * 8]);
        ovt[dt] = mfma16x16x32(vf, pf, ovt[dt]);
      }
    }
  }

  lrun += __shfl_xor(lrun, 16);
  lrun += __shfl_xor(lrun, 32);
  float rinv = 1.0f / lrun;
  long orow = ((long)(b * 2048 + q0 + l15)) * 1024 + h * 64;
#pragma unroll
  for (int dt = 0; dt < 4; ++dt) {
    ushort4 w4;
    w4.x = f2bf(ovt[dt][0] * rinv);
    w4.y = f2bf(ovt[dt][1] * rinv);
    w4.z = f2bf(ovt[dt][2] * rinv);
    w4.w = f2bf(ovt[dt][3] * rinv);
    *(ushort4*)&o[orow + dt * 16 + g * 4] = w4;
  }
}

// ---------- launcher ----------
extern "C" void kernel_launch(void* const* d_in, const int* in_sizes, int n_in,
                              void* d_out, int out_size, void* d_ws, size_t ws_size,
                              hipStream_t stream) {
  const float* x      = (const float*)d_in[0];
  const float* sin_t  = (const float*)d_in[1];
  const float* cos_t  = (const float*)d_in[2];
  const float* w_qkv  = (const float*)d_in[3];
  const float* w_proj = (const float*)d_in[4];
  const float* b_proj = (const float*)d_in[5];
  float* out = (float*)d_out;

  char* ws = (char*)d_ws;
  unsigned short* xb     = (unsigned short*)(ws);                 // 16 MiB
  unsigned short* wqkvb  = (unsigned short*)(ws + (16l << 20));   // 6 MiB
  unsigned short* wprojb = (unsigned short*)(ws + (22l << 20));   // 2 MiB
  unsigned short* Qh     = (unsigned short*)(ws + (24l << 20));   // 16 MiB
  unsigned short* Ql     = (unsigned short*)(ws + (40l << 20));   // 16 MiB
  unsigned short* Kh     = (unsigned short*)(ws + (56l << 20));   // 16 MiB
  unsigned short* Kl     = (unsigned short*)(ws + (72l << 20));   // 16 MiB
  unsigned short* Vb     = (unsigned short*)(ws + (88l << 20));   // 16 MiB
  unsigned short* ob     = xb;   // alias: xb dead after QKV GEMM

  k_f32_to_bf16<<<8192, 256, 0, stream>>>(x, xb, 8388608 / 4);
  k_f32_to_bf16<<<3072, 256, 0, stream>>>(w_qkv, wqkvb, 3145728 / 4);
  k_f32_to_bf16<<<1024, 256, 0, stream>>>(w_proj, wprojb, 1048576 / 4);

  // qkv GEMM + fused RoPE + split-pack epilogue
  k_gemm_qkv<<<dim3(24, 64), 256, 0, stream>>>(xb, wqkvb, Qh, Ql, Kh, Kl, Vb,
                                               sin_t, cos_t);
  k_flash<<<dim3(32, 64), 256, 0, stream>>>(Qh, Ql, Kh, Kl, Vb, ob);
  // out = o . w_proj^T + bias
  k_gemm_proj<<<dim3(8, 64), 256, 0, stream>>>(ob, wprojb, out, b_proj,
                                               8192, 1024, 1024);
}